// Round 14
// baseline (2211.696 us; speedup 1.0000x reference)
//
#include <hip/hip_runtime.h>
#include <stdint.h>

typedef __attribute__((ext_vector_type(4))) float f32x4;
typedef __attribute__((ext_vector_type(8))) short bf16x8;
typedef __attribute__((ext_vector_type(4))) unsigned int u32x4;
typedef __attribute__((ext_vector_type(2))) unsigned int u32x2;
typedef __attribute__((ext_vector_type(4))) unsigned short u16x4;
typedef unsigned short ushort_t;

#define B_N 32
#define T_N 1024
#define D_N 512
#define H_N 512
#define G4H 2048

__device__ __forceinline__ ushort_t f2bf(float f) {
    union { float f; unsigned int u; } v; v.f = f;
    unsigned int r = v.u + 0x7FFFu + ((v.u >> 16) & 1u);   // RNE
    return (ushort_t)(r >> 16);
}
__device__ __forceinline__ float bf2f(ushort_t b) {
    union { unsigned int u; float f; } v; v.u = ((unsigned int)b) << 16;
    return v.f;
}
// fast sigmoid/tanh via v_exp_f32 + v_rcp_f32 (~1e-6 rel err << bf16 eps)
__device__ __forceinline__ float fsig(float x) {
    return __builtin_amdgcn_rcpf(1.f + __expf(-x));
}
__device__ __forceinline__ float ftanh(float x) {
    return 1.f - 2.f * __builtin_amdgcn_rcpf(1.f + __expf(2.f * x));
}

// ---------------------------------------------------------------------------
// prep: fp32 -> bf16 of W_ih, W_hh; bias_sum; zero tagged ring EVERY launch
// (ws persists across graph replays; stale tags would corrupt this run).
// ---------------------------------------------------------------------------
__global__ __launch_bounds__(256) void prep_kernel(
    const float* __restrict__ wih, const float* __restrict__ whh,
    const float* __restrict__ bih, const float* __restrict__ bhh,
    ushort_t* __restrict__ wihb, ushort_t* __restrict__ whhb,
    float* __restrict__ bias, unsigned int* __restrict__ ringu)
{
    size_t i = (size_t)blockIdx.x * 256 + threadIdx.x;
    if (i < 2048) bias[i] = bih[i] + bhh[i];
    if (i < 32768) ringu[i] = 0u;                    // tag 0 = never valid
    const size_t NW = (size_t)G4H * D_N / 4;         // 262144 quads
    if (i < NW) {
        f32x4 v = ((const f32x4*)wih)[i];
        u16x4 o; o[0]=f2bf(v[0]); o[1]=f2bf(v[1]); o[2]=f2bf(v[2]); o[3]=f2bf(v[3]);
        ((u16x4*)wihb)[i] = o;
    } else if (i < 2 * NW) {
        size_t j = i - NW;
        f32x4 v = ((const f32x4*)whh)[j];
        u16x4 o; o[0]=f2bf(v[0]); o[1]=f2bf(v[1]); o[2]=f2bf(v[2]); o[3]=f2bf(v[3]);
        ((u16x4*)whhb)[j] = o;
    }
}

// ---------------------------------------------------------------------------
// xg = x @ W_ih^T + (b_ih+b_hh), stored bf16 as [T][B][4H]. (unchanged R10)
// ---------------------------------------------------------------------------
__global__ __launch_bounds__(512, 1) void xg_gemm(
    const float* __restrict__ x,        // [B][T][D] fp32
    const ushort_t* __restrict__ wihb,  // [4H][D] bf16
    const float* __restrict__ bias,     // [4H]
    ushort_t* __restrict__ xg)          // [T][B][4H] bf16
{
    const int tc = blockIdx.x >> 3;     // 0..63  (t-chunk of 16)
    const int gb = blockIdx.x & 7;      // 0..7   (gate-chunk of 256)
    const int tid = threadIdx.x;
    const int w = tid >> 6, l = tid & 63, lr = l & 15, lk = l >> 4;

    __shared__ ushort_t xs[16 * 520];   // 16 t-rows x 512 d (+8 pad) bf16

    const int r0 = gb * 256 + w * 16;
    const int r1 = r0 + 128;
    bf16x8 a0[16], a1[16];
#pragma unroll
    for (int kk = 0; kk < 16; ++kk) {
        a0[kk] = *(const bf16x8*)(wihb + (size_t)(r0 + lr) * D_N + kk * 32 + lk * 8);
        a1[kk] = *(const bf16x8*)(wihb + (size_t)(r1 + lr) * D_N + kk * 32 + lk * 8);
    }
    float bs0[4], bs1[4];
#pragma unroll
    for (int j = 0; j < 4; ++j) {
        bs0[j] = bias[r0 + lk * 4 + j];
        bs1[j] = bias[r1 + lk * 4 + j];
    }

    const int srow = tid >> 5;          // 0..15 (staging row = t-offset)
    const int sq   = tid & 31;          // 0..31

    for (int b = 0; b < B_N; ++b) {
        const float* xr = x + ((size_t)b * T_N + tc * 16 + srow) * D_N;
#pragma unroll
        for (int c = 0; c < 4; ++c) {
            f32x4 v = *(const f32x4*)(xr + c * 128 + sq * 4);
            u16x4 o; o[0]=f2bf(v[0]); o[1]=f2bf(v[1]); o[2]=f2bf(v[2]); o[3]=f2bf(v[3]);
            *(u16x4*)(xs + srow * 520 + c * 128 + sq * 4) = o;
        }
        __syncthreads();

        f32x4 c0, c1;
#pragma unroll
        for (int j = 0; j < 4; ++j) { c0[j] = 0.f; c1[j] = 0.f; }
#pragma unroll
        for (int kk = 0; kk < 16; ++kk) {
            bf16x8 bf = *(const bf16x8*)((const char*)xs + lr * 1040 + kk * 64 + lk * 16);
            c0 = __builtin_amdgcn_mfma_f32_16x16x32_bf16(a0[kk], bf, c0, 0, 0, 0);
            c1 = __builtin_amdgcn_mfma_f32_16x16x32_bf16(a1[kk], bf, c1, 0, 0, 0);
        }

        const int t = tc * 16 + lr;
        ushort_t* op = xg + (size_t)t * (B_N * G4H) + (size_t)b * G4H;
        u16x4 o0, o1;
#pragma unroll
        for (int j = 0; j < 4; ++j) {
            o0[j] = f2bf(c0[j] + bs0[j]);
            o1[j] = f2bf(c1[j] + bs1[j]);
        }
        *(u16x4*)(op + r0 + lk * 4) = o0;
        *(u16x4*)(op + r1 + lk * 4) = o1;
        __syncthreads();   // protect LDS before next stage
    }
}

// ---------------------------------------------------------------------------
// Sequential LSTM recurrence — R13 (proven, 2024us) + ONE change: a fixed
// s_sleep(4) (~256cy) before the FIRST poll attempt. Timing analysis: the
// first poll previously sampled the coherence point at ~ the same instant
// the slowest remote publish commits (coin flip); a miss costs a full extra
// RT (~0.9us). Delaying the first issue past the commit window makes
// attempt 1 win almost always. Bounded downside: +0.11us/step if attempt 1
// already always won. (R11 issued earlier -> always missed; R12 resampled
// faster -> fabric congestion; this is the untested point between them.)
// ---------------------------------------------------------------------------
__global__ __launch_bounds__(512, 1) void lstm_rec(
    const ushort_t* __restrict__ xg,    // [T][B][4H] bf16 (bias folded)
    const ushort_t* __restrict__ whhb,  // [4H][H] bf16
    unsigned int* __restrict__ ringu,   // [8 grp][2 par][4 batch][512 col] u32
    float* __restrict__ out,            // [B][T][H]
    float* __restrict__ hn,             // [B][H]
    float* __restrict__ cn)             // [B][H]
{
    const int tid = threadIdx.x;
    const int g = blockIdx.x >> 4;
    const int s = blockIdx.x & 15;
    const int w = tid >> 6, l = tid & 63, lr = l & 15, lk = l >> 4;

    __shared__ ushort_t hstage[4][544];   // packed h(t-1); row stride 1088 B

    // ---- persistent W_hh fragments (B operand)
    const int col4 = s * 32 + w * 4;               // this wave's 4 h-cols
    const int gc = (lr >> 2) * 512 + col4 + (lr & 3);
    bf16x8 wfrag[16];
#pragma unroll
    for (int kk = 0; kk < 16; ++kk)
        wfrag[kk] = *(const bf16x8*)(whhb + (size_t)gc * H_N + kk * 32 + lk * 8);

    float c_reg[4] = {0.f, 0.f, 0.f, 0.f};
    unsigned int* ringg = ringu + g * 4096;
    const ushort_t* xgp = xg + (size_t)(g * 4) * G4H + gc;   // + t*B*4H

    ushort_t xw[4];
#pragma unroll
    for (int j = 0; j < 4; ++j) xw[j] = xgp[(size_t)j * G4H];   // xg(t=0)

    for (int t = 0; t < T_N; ++t) {
        f32x4 acc0, acc1, acc2, acc3;
#pragma unroll
        for (int j = 0; j < 4; ++j) {
            acc0[j] = bf2f(xw[j]);
            acc1[j] = 0.f; acc2[j] = 0.f; acc3[j] = 0.f;
        }

        if (t > 0) {
            if (tid < 64) {
                // ---- poller wave: validate + stage h(t-1)
                const unsigned int* pp0 = ringg + ((t - 1) & 1) * 2048 + l * 8;
                const unsigned int* pp1 = pp0 + 1024;
                const unsigned int tp = ((unsigned int)t) << 16;
                u32x4 a[8];
                int guard = 0;
                __builtin_amdgcn_s_sleep(4);   // shift sample past remote commit
                for (;;) {
                    asm volatile(
                        "global_load_dwordx4 %0, %8, off sc0 sc1\n\t"
                        "global_load_dwordx4 %1, %8, off offset:16 sc0 sc1\n\t"
                        "global_load_dwordx4 %2, %8, off offset:2048 sc0 sc1\n\t"
                        "global_load_dwordx4 %3, %8, off offset:2064 sc0 sc1\n\t"
                        "global_load_dwordx4 %4, %9, off sc0 sc1\n\t"
                        "global_load_dwordx4 %5, %9, off offset:16 sc0 sc1\n\t"
                        "global_load_dwordx4 %6, %9, off offset:2048 sc0 sc1\n\t"
                        "global_load_dwordx4 %7, %9, off offset:2064 sc0 sc1\n\t"
                        "s_waitcnt vmcnt(0)"
                        : "=&v"(a[0]), "=&v"(a[1]), "=&v"(a[2]), "=&v"(a[3]),
                          "=&v"(a[4]), "=&v"(a[5]), "=&v"(a[6]), "=&v"(a[7])
                        : "v"(pp0), "v"(pp1)
                        : "memory");
                    unsigned int d = 0;
#pragma unroll
                    for (int r = 0; r < 8; ++r) {
                        d |= (a[r][0] ^ tp); d |= (a[r][1] ^ tp);
                        d |= (a[r][2] ^ tp); d |= (a[r][3] ^ tp);
                    }
                    int ok = ((d & 0xFFFF0000u) == 0u);
                    if (__all(ok) || ++guard > (1 << 16)) break;
                    __builtin_amdgcn_s_sleep(1);   // throttle: >= ~1 RT period
                }
                // ---- pack + stage (wave-contiguous ds_write_b128)
#pragma unroll
                for (int n = 0; n < 4; ++n) {
                    u32x4 p;
                    p[0] = __builtin_amdgcn_perm(a[2*n][1], a[2*n][0], 0x05040100u);
                    p[1] = __builtin_amdgcn_perm(a[2*n][3], a[2*n][2], 0x05040100u);
                    p[2] = __builtin_amdgcn_perm(a[2*n+1][1], a[2*n+1][0], 0x05040100u);
                    p[3] = __builtin_amdgcn_perm(a[2*n+1][3], a[2*n+1][2], 0x05040100u);
                    *(u32x4*)((char*)hstage + n * 1088 + l * 16) = p;
                }
            }
            __syncthreads();   // barrier: stage ready (the only barrier/step)

            const char* ap = (const char*)hstage + (lr & 3) * 1088 + lk * 16;
#pragma unroll
            for (int kk = 0; kk < 16; ++kk) {
                bf16x8 af = *(const bf16x8*)(ap + kk * 64);
                switch (kk & 3) {
                case 0: acc0 = __builtin_amdgcn_mfma_f32_16x16x32_bf16(af, wfrag[kk], acc0, 0, 0, 0); break;
                case 1: acc1 = __builtin_amdgcn_mfma_f32_16x16x32_bf16(af, wfrag[kk], acc1, 0, 0, 0); break;
                case 2: acc2 = __builtin_amdgcn_mfma_f32_16x16x32_bf16(af, wfrag[kk], acc2, 0, 0, 0); break;
                default: acc3 = __builtin_amdgcn_mfma_f32_16x16x32_bf16(af, wfrag[kk], acc3, 0, 0, 0); break;
                }
            }
        } else {
            __syncthreads();   // uniform barrier structure
        }

#pragma unroll
        for (int j = 0; j < 4; ++j)
            acc0[j] += (acc1[j] + acc2[j]) + acc3[j];

        // ---- in-wave cell: activation per gate lane, then 3 shuffles
        const int q = (l >> 2) & 3;
        float av[4];
#pragma unroll
        for (int j = 0; j < 4; ++j)
            av[j] = (q == 2) ? ftanh(acc0[j]) : fsig(acc0[j]);

        float hv[4];
#pragma unroll
        for (int j = 0; j < 4; ++j) {
            float f_ = __shfl_xor(av[j], 4);
            float g_ = __shfl_xor(av[j], 8);
            float o_ = __shfl_xor(av[j], 12);
            c_reg[j] = f_ * c_reg[j] + av[j] * g_;
            hv[j] = o_ * ftanh(c_reg[j]);
        }

        // ---- publish (lanes 0-3 of every wave: col = col4 + l)
        if (l < 4) {
            unsigned int* rp = ringg + (t & 1) * 2048 + col4 + l;
            const unsigned int tag = ((unsigned int)(t + 1)) << 16;
#pragma unroll
            for (int j = 0; j < 4; ++j) {
                unsigned int hw = tag | (unsigned int)f2bf(hv[j]);
                asm volatile("global_store_dword %0, %1, off sc0 sc1"
                             :: "v"(rp + j * 512), "v"(hw) : "memory");
            }
            float* op = out + (size_t)(g * 4) * T_N * H_N + (size_t)t * H_N + col4 + l;
#pragma unroll
            for (int j = 0; j < 4; ++j)
                op[(size_t)j * T_N * H_N] = hv[j];
            if (t == T_N - 1) {
#pragma unroll
                for (int j = 0; j < 4; ++j) {
                    size_t bi = (size_t)(g * 4 + j) * H_N + col4 + l;
                    hn[bi] = hv[j];
                    cn[bi] = c_reg[j];
                }
            }
        }

        // ---- xg prefetch for t+1 (plain cached loads; latency hides under
        // the publish tail and next step's poll)
        if (t < T_N - 1) {
            const ushort_t* xa = xgp + (size_t)(t + 1) * (B_N * G4H);
#pragma unroll
            for (int j = 0; j < 4; ++j) xw[j] = xa[(size_t)j * G4H];
        }
    }
}

// ---------------------------------------------------------------------------
extern "C" void kernel_launch(void* const* d_in, const int* in_sizes, int n_in,
                              void* d_out, int out_size, void* d_ws, size_t ws_size,
                              hipStream_t stream) {
    (void)in_sizes; (void)n_in; (void)out_size; (void)ws_size;
    const float* x   = (const float*)d_in[0];
    const float* wih = (const float*)d_in[1];
    const float* whh = (const float*)d_in[2];
    const float* bih = (const float*)d_in[3];
    const float* bhh = (const float*)d_in[4];
    float* out = (float*)d_out;
    float* hn  = out + (size_t)B_N * T_N * H_N;
    float* cn  = hn + (size_t)B_N * H_N;

    char* ws = (char*)d_ws;
    // ws layout:
    ushort_t*     xg    = (ushort_t*)    (ws);                  // 134217728 B
    ushort_t*     wihb  = (ushort_t*)    (ws + 167772160);      //   2097152 B
    ushort_t*     whhb  = (ushort_t*)    (ws + 169869312);      //   2097152 B
    float*        bias  = (float*)       (ws + 171966464);      //      8192 B
    unsigned int* ringu = (unsigned int*)(ws + 171974656);      //    131072 B

    prep_kernel<<<2048, 256, 0, stream>>>(wih, whh, bih, bhh,
                                          wihb, whhb, bias, ringu);
    xg_gemm<<<512, 512, 0, stream>>>(x, wihb, bias, xg);
    lstm_rec<<<128, 512, 0, stream>>>(xg, whhb, ringu, out, hn, cn);
}

// Round 15
// 2144.183 us; speedup vs baseline: 1.0315x; 1.0315x over previous
//
#include <hip/hip_runtime.h>
#include <stdint.h>

typedef __attribute__((ext_vector_type(4))) float f32x4;
typedef __attribute__((ext_vector_type(8))) short bf16x8;
typedef __attribute__((ext_vector_type(4))) unsigned int u32x4;
typedef __attribute__((ext_vector_type(2))) unsigned int u32x2;
typedef __attribute__((ext_vector_type(4))) unsigned short u16x4;
typedef unsigned short ushort_t;

#define B_N 32
#define T_N 1024
#define D_N 512
#define H_N 512
#define G4H 2048

__device__ __forceinline__ ushort_t f2bf(float f) {
    union { float f; unsigned int u; } v; v.f = f;
    unsigned int r = v.u + 0x7FFFu + ((v.u >> 16) & 1u);   // RNE
    return (ushort_t)(r >> 16);
}
__device__ __forceinline__ float bf2f(ushort_t b) {
    union { unsigned int u; float f; } v; v.u = ((unsigned int)b) << 16;
    return v.f;
}
// fast sigmoid/tanh via v_exp_f32 + v_rcp_f32 (~1e-6 rel err << bf16 eps)
__device__ __forceinline__ float fsig(float x) {
    return __builtin_amdgcn_rcpf(1.f + __expf(-x));
}
__device__ __forceinline__ float ftanh(float x) {
    return 1.f - 2.f * __builtin_amdgcn_rcpf(1.f + __expf(2.f * x));
}

// ---------------------------------------------------------------------------
// prep: fp32 -> bf16 of W_ih, W_hh; bias_sum; zero tagged ring EVERY launch
// (ws persists across graph replays; stale tags would corrupt this run).
// ---------------------------------------------------------------------------
__global__ __launch_bounds__(256) void prep_kernel(
    const float* __restrict__ wih, const float* __restrict__ whh,
    const float* __restrict__ bih, const float* __restrict__ bhh,
    ushort_t* __restrict__ wihb, ushort_t* __restrict__ whhb,
    float* __restrict__ bias, unsigned int* __restrict__ ringu)
{
    size_t i = (size_t)blockIdx.x * 256 + threadIdx.x;
    if (i < 2048) bias[i] = bih[i] + bhh[i];
    if (i < 32768) ringu[i] = 0u;                    // tag 0 = never valid
    const size_t NW = (size_t)G4H * D_N / 4;         // 262144 quads
    if (i < NW) {
        f32x4 v = ((const f32x4*)wih)[i];
        u16x4 o; o[0]=f2bf(v[0]); o[1]=f2bf(v[1]); o[2]=f2bf(v[2]); o[3]=f2bf(v[3]);
        ((u16x4*)wihb)[i] = o;
    } else if (i < 2 * NW) {
        size_t j = i - NW;
        f32x4 v = ((const f32x4*)whh)[j];
        u16x4 o; o[0]=f2bf(v[0]); o[1]=f2bf(v[1]); o[2]=f2bf(v[2]); o[3]=f2bf(v[3]);
        ((u16x4*)whhb)[j] = o;
    }
}

// ---------------------------------------------------------------------------
// xg = x @ W_ih^T + (b_ih+b_hh), stored bf16 as [T][B][4H].
// ---------------------------------------------------------------------------
__global__ __launch_bounds__(512, 1) void xg_gemm(
    const float* __restrict__ x,        // [B][T][D] fp32
    const ushort_t* __restrict__ wihb,  // [4H][D] bf16
    const float* __restrict__ bias,     // [4H]
    ushort_t* __restrict__ xg)          // [T][B][4H] bf16
{
    const int tc = blockIdx.x >> 3;     // 0..63  (t-chunk of 16)
    const int gb = blockIdx.x & 7;      // 0..7   (gate-chunk of 256)
    const int tid = threadIdx.x;
    const int w = tid >> 6, l = tid & 63, lr = l & 15, lk = l >> 4;

    __shared__ ushort_t xs[16 * 520];   // 16 t-rows x 512 d (+8 pad) bf16

    const int r0 = gb * 256 + w * 16;
    const int r1 = r0 + 128;
    bf16x8 a0[16], a1[16];
#pragma unroll
    for (int kk = 0; kk < 16; ++kk) {
        a0[kk] = *(const bf16x8*)(wihb + (size_t)(r0 + lr) * D_N + kk * 32 + lk * 8);
        a1[kk] = *(const bf16x8*)(wihb + (size_t)(r1 + lr) * D_N + kk * 32 + lk * 8);
    }
    float bs0[4], bs1[4];
#pragma unroll
    for (int j = 0; j < 4; ++j) {
        bs0[j] = bias[r0 + lk * 4 + j];
        bs1[j] = bias[r1 + lk * 4 + j];
    }

    const int srow = tid >> 5;          // 0..15 (staging row = t-offset)
    const int sq   = tid & 31;          // 0..31

    for (int b = 0; b < B_N; ++b) {
        const float* xr = x + ((size_t)b * T_N + tc * 16 + srow) * D_N;
#pragma unroll
        for (int c = 0; c < 4; ++c) {
            f32x4 v = *(const f32x4*)(xr + c * 128 + sq * 4);
            u16x4 o; o[0]=f2bf(v[0]); o[1]=f2bf(v[1]); o[2]=f2bf(v[2]); o[3]=f2bf(v[3]);
            *(u16x4*)(xs + srow * 520 + c * 128 + sq * 4) = o;
        }
        __syncthreads();

        f32x4 c0, c1;
#pragma unroll
        for (int j = 0; j < 4; ++j) { c0[j] = 0.f; c1[j] = 0.f; }
#pragma unroll
        for (int kk = 0; kk < 16; ++kk) {
            bf16x8 bf = *(const bf16x8*)((const char*)xs + lr * 1040 + kk * 64 + lk * 16);
            c0 = __builtin_amdgcn_mfma_f32_16x16x32_bf16(a0[kk], bf, c0, 0, 0, 0);
            c1 = __builtin_amdgcn_mfma_f32_16x16x32_bf16(a1[kk], bf, c1, 0, 0, 0);
        }

        const int t = tc * 16 + lr;
        ushort_t* op = xg + (size_t)t * (B_N * G4H) + (size_t)b * G4H;
        u16x4 o0, o1;
#pragma unroll
        for (int j = 0; j < 4; ++j) {
            o0[j] = f2bf(c0[j] + bs0[j]);
            o1[j] = f2bf(c1[j] + bs1[j]);
        }
        *(u16x4*)(op + r0 + lk * 4) = o0;
        *(u16x4*)(op + r1 + lk * 4) = o1;
        __syncthreads();   // protect LDS before next stage
    }
}

// ---------------------------------------------------------------------------
// Sequential LSTM recurrence — the measured-best structure (R13, 2024us):
// tagged-data ring (word = ((t+1)<<16)|bf16(h): data+freshness in one
// store, staleness -> retry never corruption), one poller wave per block
// with {issue 8 loads, vmcnt(0), tag-check} per attempt and s_sleep(1)
// between failed attempts (sampling faster congests the fabric - R12;
// sampling earlier always misses - R11; sampling later is pure cost - R14),
// wave-contiguous LDS stage (0 bank conflicts), one barrier/step, in-wave
// gate exchange via 3 __shfl_xor, 4 independent MFMA accumulator chains,
// xg prefetch at loop bottom.
// ---------------------------------------------------------------------------
__global__ __launch_bounds__(512, 1) void lstm_rec(
    const ushort_t* __restrict__ xg,    // [T][B][4H] bf16 (bias folded)
    const ushort_t* __restrict__ whhb,  // [4H][H] bf16
    unsigned int* __restrict__ ringu,   // [8 grp][2 par][4 batch][512 col] u32
    float* __restrict__ out,            // [B][T][H]
    float* __restrict__ hn,             // [B][H]
    float* __restrict__ cn)             // [B][H]
{
    const int tid = threadIdx.x;
    const int g = blockIdx.x >> 4;
    const int s = blockIdx.x & 15;
    const int w = tid >> 6, l = tid & 63, lr = l & 15, lk = l >> 4;

    __shared__ ushort_t hstage[4][544];   // packed h(t-1); row stride 1088 B

    // ---- persistent W_hh fragments (B operand)
    const int col4 = s * 32 + w * 4;               // this wave's 4 h-cols
    const int gc = (lr >> 2) * 512 + col4 + (lr & 3);
    bf16x8 wfrag[16];
#pragma unroll
    for (int kk = 0; kk < 16; ++kk)
        wfrag[kk] = *(const bf16x8*)(whhb + (size_t)gc * H_N + kk * 32 + lk * 8);

    float c_reg[4] = {0.f, 0.f, 0.f, 0.f};
    unsigned int* ringg = ringu + g * 4096;
    const ushort_t* xgp = xg + (size_t)(g * 4) * G4H + gc;   // + t*B*4H

    ushort_t xw[4];
#pragma unroll
    for (int j = 0; j < 4; ++j) xw[j] = xgp[(size_t)j * G4H];   // xg(t=0)

    for (int t = 0; t < T_N; ++t) {
        f32x4 acc0, acc1, acc2, acc3;
#pragma unroll
        for (int j = 0; j < 4; ++j) {
            acc0[j] = bf2f(xw[j]);
            acc1[j] = 0.f; acc2[j] = 0.f; acc3[j] = 0.f;
        }

        if (t > 0) {
            if (tid < 64) {
                // ---- poller wave: validate + stage h(t-1)
                const unsigned int* pp0 = ringg + ((t - 1) & 1) * 2048 + l * 8;
                const unsigned int* pp1 = pp0 + 1024;
                const unsigned int tp = ((unsigned int)t) << 16;
                u32x4 a[8];
                int guard = 0;
                for (;;) {
                    asm volatile(
                        "global_load_dwordx4 %0, %8, off sc0 sc1\n\t"
                        "global_load_dwordx4 %1, %8, off offset:16 sc0 sc1\n\t"
                        "global_load_dwordx4 %2, %8, off offset:2048 sc0 sc1\n\t"
                        "global_load_dwordx4 %3, %8, off offset:2064 sc0 sc1\n\t"
                        "global_load_dwordx4 %4, %9, off sc0 sc1\n\t"
                        "global_load_dwordx4 %5, %9, off offset:16 sc0 sc1\n\t"
                        "global_load_dwordx4 %6, %9, off offset:2048 sc0 sc1\n\t"
                        "global_load_dwordx4 %7, %9, off offset:2064 sc0 sc1\n\t"
                        "s_waitcnt vmcnt(0)"
                        : "=&v"(a[0]), "=&v"(a[1]), "=&v"(a[2]), "=&v"(a[3]),
                          "=&v"(a[4]), "=&v"(a[5]), "=&v"(a[6]), "=&v"(a[7])
                        : "v"(pp0), "v"(pp1)
                        : "memory");
                    unsigned int d = 0;
#pragma unroll
                    for (int r = 0; r < 8; ++r) {
                        d |= (a[r][0] ^ tp); d |= (a[r][1] ^ tp);
                        d |= (a[r][2] ^ tp); d |= (a[r][3] ^ tp);
                    }
                    int ok = ((d & 0xFFFF0000u) == 0u);
                    if (__all(ok) || ++guard > (1 << 16)) break;
                    __builtin_amdgcn_s_sleep(1);   // throttle: >= ~1 RT period
                }
                // ---- pack + stage (wave-contiguous ds_write_b128)
#pragma unroll
                for (int n = 0; n < 4; ++n) {
                    u32x4 p;
                    p[0] = __builtin_amdgcn_perm(a[2*n][1], a[2*n][0], 0x05040100u);
                    p[1] = __builtin_amdgcn_perm(a[2*n][3], a[2*n][2], 0x05040100u);
                    p[2] = __builtin_amdgcn_perm(a[2*n+1][1], a[2*n+1][0], 0x05040100u);
                    p[3] = __builtin_amdgcn_perm(a[2*n+1][3], a[2*n+1][2], 0x05040100u);
                    *(u32x4*)((char*)hstage + n * 1088 + l * 16) = p;
                }
            }
            __syncthreads();   // barrier: stage ready (the only barrier/step)

            const char* ap = (const char*)hstage + (lr & 3) * 1088 + lk * 16;
#pragma unroll
            for (int kk = 0; kk < 16; ++kk) {
                bf16x8 af = *(const bf16x8*)(ap + kk * 64);
                switch (kk & 3) {
                case 0: acc0 = __builtin_amdgcn_mfma_f32_16x16x32_bf16(af, wfrag[kk], acc0, 0, 0, 0); break;
                case 1: acc1 = __builtin_amdgcn_mfma_f32_16x16x32_bf16(af, wfrag[kk], acc1, 0, 0, 0); break;
                case 2: acc2 = __builtin_amdgcn_mfma_f32_16x16x32_bf16(af, wfrag[kk], acc2, 0, 0, 0); break;
                default: acc3 = __builtin_amdgcn_mfma_f32_16x16x32_bf16(af, wfrag[kk], acc3, 0, 0, 0); break;
                }
            }
        } else {
            __syncthreads();   // uniform barrier structure
        }

#pragma unroll
        for (int j = 0; j < 4; ++j)
            acc0[j] += (acc1[j] + acc2[j]) + acc3[j];

        // ---- in-wave cell: activation per gate lane, then 3 shuffles
        const int q = (l >> 2) & 3;
        float av[4];
#pragma unroll
        for (int j = 0; j < 4; ++j)
            av[j] = (q == 2) ? ftanh(acc0[j]) : fsig(acc0[j]);

        float hv[4];
#pragma unroll
        for (int j = 0; j < 4; ++j) {
            float f_ = __shfl_xor(av[j], 4);
            float g_ = __shfl_xor(av[j], 8);
            float o_ = __shfl_xor(av[j], 12);
            c_reg[j] = f_ * c_reg[j] + av[j] * g_;
            hv[j] = o_ * ftanh(c_reg[j]);
        }

        // ---- publish (lanes 0-3 of every wave: col = col4 + l)
        if (l < 4) {
            unsigned int* rp = ringg + (t & 1) * 2048 + col4 + l;
            const unsigned int tag = ((unsigned int)(t + 1)) << 16;
#pragma unroll
            for (int j = 0; j < 4; ++j) {
                unsigned int hw = tag | (unsigned int)f2bf(hv[j]);
                asm volatile("global_store_dword %0, %1, off sc0 sc1"
                             :: "v"(rp + j * 512), "v"(hw) : "memory");
            }
            float* op = out + (size_t)(g * 4) * T_N * H_N + (size_t)t * H_N + col4 + l;
#pragma unroll
            for (int j = 0; j < 4; ++j)
                op[(size_t)j * T_N * H_N] = hv[j];
            if (t == T_N - 1) {
#pragma unroll
                for (int j = 0; j < 4; ++j) {
                    size_t bi = (size_t)(g * 4 + j) * H_N + col4 + l;
                    hn[bi] = hv[j];
                    cn[bi] = c_reg[j];
                }
            }
        }

        // ---- xg prefetch for t+1 (plain cached loads; latency hides under
        // the publish tail and next step's poll)
        if (t < T_N - 1) {
            const ushort_t* xa = xgp + (size_t)(t + 1) * (B_N * G4H);
#pragma unroll
            for (int j = 0; j < 4; ++j) xw[j] = xa[(size_t)j * G4H];
        }
    }
}

// ---------------------------------------------------------------------------
extern "C" void kernel_launch(void* const* d_in, const int* in_sizes, int n_in,
                              void* d_out, int out_size, void* d_ws, size_t ws_size,
                              hipStream_t stream) {
    (void)in_sizes; (void)n_in; (void)out_size; (void)ws_size;
    const float* x   = (const float*)d_in[0];
    const float* wih = (const float*)d_in[1];
    const float* whh = (const float*)d_in[2];
    const float* bih = (const float*)d_in[3];
    const float* bhh = (const float*)d_in[4];
    float* out = (float*)d_out;
    float* hn  = out + (size_t)B_N * T_N * H_N;
    float* cn  = hn + (size_t)B_N * H_N;

    char* ws = (char*)d_ws;
    // ws layout:
    ushort_t*     xg    = (ushort_t*)    (ws);                  // 134217728 B
    ushort_t*     wihb  = (ushort_t*)    (ws + 167772160);      //   2097152 B
    ushort_t*     whhb  = (ushort_t*)    (ws + 169869312);      //   2097152 B
    float*        bias  = (float*)       (ws + 171966464);      //      8192 B
    unsigned int* ringu = (unsigned int*)(ws + 171974656);      //    131072 B

    prep_kernel<<<2048, 256, 0, stream>>>(wih, whh, bih, bhh,
                                          wihb, whhb, bias, ringu);
    xg_gemm<<<512, 512, 0, stream>>>(x, wihb, bias, xg);
    lstm_rec<<<128, 512, 0, stream>>>(xg, whhb, ringu, out, hn, cn);
}